// Round 2
// baseline (924.301 us; speedup 1.0000x reference)
//
#include <hip/hip_runtime.h>
#include <math.h>

#define NN 100000
#define NE 3200000
#define FIN 512
#define NH 8
#define C1 8
#define HC1 64
#define C2 10
#define HC2 80

// radix CSR build
#define EPB 4096
#define NBLK 782           // ceil(NE/EPB)
#define NBUK 196           // ceil(NN/512)
#define SCN (NBUK * NBLK)  // 153272
#define SCNB 150           // ceil(SCN/1024)
#define AGGB 1568          // (NBUK*512)/64 blocks, 4 waves x 16 nodes each

typedef unsigned int uint;
typedef unsigned short ushort;
using bf16x8 = __attribute__((ext_vector_type(8))) short;
using f32x4  = __attribute__((ext_vector_type(4))) float;

// ---------------- static scratch ----------------
__device__ float g_h1[NN * HC1];        // x @ W1 (fp32, MFMA out)
__device__ float g_hact[NN * HC1];      // elu(agg1 + b1)
__device__ float g_h2[NN * HC2];        // hact @ W2 (fp32)
__device__ uint  g_h1b[NN * 32];        // h1 as bf16 pairs (ch 2p, 2p+1)
__device__ uint  g_h2b[NN * 40];        // h2 as bf16 pairs
__device__ uint  g_w1bt[64 * 256];      // W1 transposed bf16 pairs: [n][kp]
__device__ float g_ssrc[NN * NH];
__device__ float g_sdst[NN * NH];
__device__ int   g_off8[NBUK * 4096 + 1]; // per-(bucket, range, node) CSR starts
__device__ uint  g_pscan[SCN];          // per-(bucket,block) counts -> scanned
__device__ uint  g_bsum2[256];
__device__ uint  g_ebuf[NE];            // packed (dlow<<17)|src, bucket-partitioned
__device__ uint  g_csr[NE];             // packed (dlow<<17)|src, (range,node)-sorted

__device__ __forceinline__ float lrelu(float x) { return fmaxf(x, 0.2f * x); }

__device__ __forceinline__ uint bf16_rne(float x) {
  uint u = __float_as_uint(x);
  u += 0x7fffu + ((u >> 16) & 1u);
  return u >> 16;
}
__device__ __forceinline__ uint packbf2(float lo, float hi) {
  return bf16_rne(lo) | (bf16_rne(hi) << 16);
}
__device__ __forceinline__ float blo(uint v) { return __uint_as_float(v << 16); }
__device__ __forceinline__ float bhi(uint v) { return __uint_as_float(v & 0xffff0000u); }

// ---------------- CSR build: radix partition by dst, no global atomics ----------
__global__ __launch_bounds__(256) void p1count_kernel(const int* __restrict__ ei) {
  __shared__ uint cnt[NBUK];
  int tid = threadIdx.x;
  for (int i = tid; i < NBUK; i += 256) cnt[i] = 0;
  __syncthreads();
  const int* dstp = ei + NE;
  int base = blockIdx.x * EPB;
#pragma unroll 4
  for (int k = 0; k < 16; k++) {
    int e = base + k * 256 + tid;
    if (e < NE) atomicAdd(&cnt[dstp[e] >> 9], 1u);
  }
  __syncthreads();
  for (int i = tid; i < NBUK; i += 256) g_pscan[i * NBLK + blockIdx.x] = cnt[i];
}

__global__ __launch_bounds__(1024) void scn_block_kernel() {
  __shared__ uint sd[1024];
  int tid = threadIdx.x;
  int i = blockIdx.x * 1024 + tid;
  uint v = (i < SCN) ? g_pscan[i] : 0;
  sd[tid] = v;
  __syncthreads();
  for (int off = 1; off < 1024; off <<= 1) {
    uint x = (tid >= off) ? sd[tid - off] : 0;
    __syncthreads();
    sd[tid] += x;
    __syncthreads();
  }
  if (i < SCN) g_pscan[i] = sd[tid] - v;  // exclusive within block
  if (tid == 1023) g_bsum2[blockIdx.x] = sd[1023];
}

__global__ void scn_tops_kernel() {  // 1 block, 256 threads
  __shared__ uint sd[256];
  int tid = threadIdx.x;
  uint v = (tid < SCNB) ? g_bsum2[tid] : 0;
  sd[tid] = v;
  __syncthreads();
  for (int off = 1; off < 256; off <<= 1) {
    uint x = (tid >= off) ? sd[tid - off] : 0;
    __syncthreads();
    sd[tid] += x;
    __syncthreads();
  }
  g_bsum2[tid] = sd[tid] - v;  // exclusive scan of block sums
}

__global__ __launch_bounds__(1024) void scn_add_kernel() {
  int i = blockIdx.x * 1024 + threadIdx.x;
  if (i < SCN) g_pscan[i] += g_bsum2[i >> 10];
}

__global__ __launch_bounds__(256) void p1scatter_kernel(const int* __restrict__ ei) {
  __shared__ uint cur[NBUK];
  int tid = threadIdx.x;
  for (int i = tid; i < NBUK; i += 256) cur[i] = g_pscan[i * NBLK + blockIdx.x];
  __syncthreads();
  const int* srcp = ei;
  const int* dstp = ei + NE;
  int base = blockIdx.x * EPB;
#pragma unroll 4
  for (int k = 0; k < 16; k++) {
    int e = base + k * 256 + tid;
    if (e < NE) {
      int d = dstp[e], s = srcp[e];
      uint pos = atomicAdd(&cur[d >> 9], 1u);  // LDS atomic
      g_ebuf[pos] = ((uint)(d & 511) << 17) | (uint)s;
    }
  }
}

// Pass 2: per-bucket 4096-bin (src-range x dlow) histogram/scan/scatter.
// Edges within a bucket come out sorted by (src-range, node): a wave owning 16
// consecutive nodes reads ONE contiguous ~64-edge run per range => 4x-unrolled
// gather MLP AND phase-synchronized range sweep (per-XCD L2 working set ~2.4MB).
__global__ __launch_bounds__(1024) void p2build_kernel() {
  __shared__ uint hist[4096];   // reused as cursors in pass 2
  __shared__ uint excl[4096];
  __shared__ uint tsum[1024];
  int tid = threadIdx.x;
  int b = blockIdx.x;
  uint bstart = g_pscan[b * NBLK];
  uint bend = (b < NBUK - 1) ? g_pscan[(b + 1) * NBLK] : NE;
  for (int i = tid; i < 4096; i += 1024) hist[i] = 0;
  __syncthreads();
  for (uint j = bstart + tid; j < bend; j += 1024) {
    uint v = g_ebuf[j];
    uint bin = (((v & 0x1FFFFu) >> 14) << 9) | (v >> 17);  // (range, node)
    atomicAdd(&hist[bin], 1u);
  }
  __syncthreads();
  uint h0 = hist[tid * 4 + 0], h1 = hist[tid * 4 + 1];
  uint h2 = hist[tid * 4 + 2], h3 = hist[tid * 4 + 3];
  uint s1 = h0 + h1, s2 = s1 + h2, s3 = s2 + h3;
  tsum[tid] = s3;
  __syncthreads();
  for (int off = 1; off < 1024; off <<= 1) {
    uint x = (tid >= off) ? tsum[tid - off] : 0;
    __syncthreads();
    tsum[tid] += x;
    __syncthreads();
  }
  uint te = tsum[tid] - s3;  // exclusive over threads
  excl[tid * 4 + 0] = te;
  excl[tid * 4 + 1] = te + h0;
  excl[tid * 4 + 2] = te + s1;
  excl[tid * 4 + 3] = te + s2;
  __syncthreads();
  for (int i = tid; i < 4096; i += 1024)
    g_off8[b * 4096 + i] = (int)(bstart + excl[i]);  // start of (range, node)
  if (b == NBUK - 1 && tid == 0) g_off8[NBUK * 4096] = NE;
  for (int i = tid; i < 4096; i += 1024) hist[i] = excl[i];  // cursors
  __syncthreads();
  for (uint j = bstart + tid; j < bend; j += 1024) {
    uint v = g_ebuf[j];
    uint bin = (((v & 0x1FFFFu) >> 14) << 9) | (v >> 17);
    uint pos = bstart + atomicAdd(&hist[bin], 1u);  // LDS atomic
    g_csr[pos] = v;  // keep packed (dlow<<17)|src
  }
}

// ---------------- W1 -> bf16 transposed pairs ----------------
__global__ __launch_bounds__(256) void w1cast_kernel(const float* __restrict__ W) {
  int idx = blockIdx.x * 256 + threadIdx.x;  // 0..16383
  int n = idx & 63, kp = idx >> 6;           // kp 0..255
  float lo = W[(2 * kp) * HC1 + n];
  float hi = W[(2 * kp + 1) * HC1 + n];
  g_w1bt[n * 256 + kp] = packbf2(lo, hi);
}

// ---------------- GEMM1: g_h1 = X[NN,512] @ W1[512,64] via bf16 MFMA ------------
__device__ __forceinline__ int sw_idx(int row, int g) {
  return row * 32 + ((g ^ (row & 7)) << 2);
}

__global__ __launch_bounds__(256) void gemm1_kernel(const float* __restrict__ X) {
  __shared__ uint sA[64 * 32];
  __shared__ uint sB[64 * 32];
  int t = threadIdx.x;
  int w = t >> 6, l = t & 63;
  int q = l >> 4, c = l & 15;
  int r0 = blockIdx.x * 64;
  int sr = t >> 2;             // 0..63 (row / n)
  int sc = t & 3;              // quarter
  int xrow = r0 + sr; if (xrow >= NN) xrow = NN - 1;
  const float* xbase = &X[(long)xrow * FIN + sc * 16];
  const uint* wbase = &g_w1bt[sr * 256 + sc * 8];
  f32x4 acc[4] = {{0.f,0.f,0.f,0.f},{0.f,0.f,0.f,0.f},{0.f,0.f,0.f,0.f},{0.f,0.f,0.f,0.f}};
  for (int k0 = 0; k0 < FIN; k0 += 64) {
    __syncthreads();
    float4 f0 = *(const float4*)&xbase[k0 + 0];
    float4 f1 = *(const float4*)&xbase[k0 + 4];
    float4 f2 = *(const float4*)&xbase[k0 + 8];
    float4 f3 = *(const float4*)&xbase[k0 + 12];
    uint4 a0 = make_uint4(packbf2(f0.x, f0.y), packbf2(f0.z, f0.w),
                          packbf2(f1.x, f1.y), packbf2(f1.z, f1.w));
    uint4 a1 = make_uint4(packbf2(f2.x, f2.y), packbf2(f2.z, f2.w),
                          packbf2(f3.x, f3.y), packbf2(f3.z, f3.w));
    *(uint4*)&sA[sw_idx(sr, sc * 2 + 0)] = a0;
    *(uint4*)&sA[sw_idx(sr, sc * 2 + 1)] = a1;
    uint4 b0 = *(const uint4*)&wbase[(k0 >> 1) + 0];
    uint4 b1 = *(const uint4*)&wbase[(k0 >> 1) + 4];
    *(uint4*)&sB[sw_idx(sr, sc * 2 + 0)] = b0;
    *(uint4*)&sB[sw_idx(sr, sc * 2 + 1)] = b1;
    __syncthreads();
#pragma unroll
    for (int ks = 0; ks < 2; ks++) {
      int g = ks * 4 + q;
      bf16x8 a = *(const bf16x8*)&sA[sw_idx(w * 16 + c, g)];
#pragma unroll
      for (int nt = 0; nt < 4; nt++) {
        bf16x8 b = *(const bf16x8*)&sB[sw_idx(nt * 16 + c, g)];
        acc[nt] = __builtin_amdgcn_mfma_f32_16x16x32_bf16(a, b, acc[nt], 0, 0, 0);
      }
    }
  }
  int orow0 = r0 + w * 16 + q * 4;
#pragma unroll
  for (int nt = 0; nt < 4; nt++) {
#pragma unroll
    for (int r = 0; r < 4; r++) {
      int row = orow0 + r;
      if (row < NN) g_h1[row * HC1 + nt * 16 + c] = acc[nt][r];
    }
  }
}

// ---------------- attention scores + bf16 packing ----------------
template <int LAYER>
__global__ __launch_bounds__(256) void s_kernel(const float* __restrict__ a_src,
                                                const float* __restrict__ a_dst) {
  constexpr int C = (LAYER == 1) ? C1 : C2;
  const float* Hm = (LAYER == 1) ? g_h1 : g_h2;
  uint* Hb = (LAYER == 1) ? g_h1b : g_h2b;
  int t = blockIdx.x * 256 + threadIdx.x;
  if (t >= NN * NH) return;
  int h = t & 7;
  const float* row = &Hm[t * C];
  float ss = 0.f, sdd = 0.f;
  float vals[C];
#pragma unroll
  for (int c = 0; c < C; c++) {
    float v = row[c];
    vals[c] = v;
    ss = fmaf(v, a_src[h * C + c], ss);
    sdd = fmaf(v, a_dst[h * C + c], sdd);
  }
  g_ssrc[t] = ss;
  g_sdst[t] = sdd;
#pragma unroll
  for (int j = 0; j < C / 2; j++)
    Hb[t * (C / 2) + j] = packbf2(vals[2 * j], vals[2 * j + 1]);
}

// ---- layer-1 aggregation: 16 nodes/wave, contiguous per-range edge runs ----
// Flat 4x-unrolled edge loop over the (range,node)-sorted run; register carry
// per current node, flushed to per-wave LDS accumulators on node change.
__global__ __launch_bounds__(256) void agg1_kernel(const float* __restrict__ b1) {
  __shared__ float lacc[4][16][64];  // per-wave node x channel accumulators
  __shared__ float lw[4][16][8];     // per-wave node x head weight sums
  __shared__ float lsd[4][16][8];    // per-wave node x head dst scores
  int tid = threadIdx.x;
  int w = tid >> 6, lane = tid & 63;
  int h = lane >> 3;
  int wv = blockIdx.x * 4 + w;
  int n0 = wv * 16;                  // first node slot (slot == node id)
  int b = n0 >> 9, nl0 = n0 & 511;
  const ushort* __restrict__ h1u = (const ushort*)g_h1b;  // bf16 channel view
#pragma unroll
  for (int s = 0; s < 16; s++) lacc[w][s][lane] = 0.f;
  for (int k = lane; k < 128; k += 64) {
    int s = k >> 3, hh = k & 7;
    int n = n0 + s; if (n >= NN) n = NN - 1;
    lsd[w][s][hh] = g_sdst[n * NH + hh];
    lw[w][s][hh] = 0.f;
  }
  int xcd = blockIdx.x & 7;
  int cur = -1;
  float acc = 0.f, aw = 0.f;
#define EDGE1(vv, ee, ff)                                    \
  {                                                          \
    int nl_ = (int)((vv) >> 17);                             \
    if (nl_ != cur) {                                        \
      if (cur >= 0) {                                        \
        lacc[w][cur - nl0][lane] += acc;                     \
        if (!(lane & 7)) lw[w][cur - nl0][h] += aw;          \
      }                                                      \
      cur = nl_; acc = 0.f; aw = 0.f;                        \
    }                                                        \
    acc = fmaf(__uint_as_float((uint)(ff) << 16), (ee), acc);\
    aw += (ee);                                              \
  }
  for (int rr = 0; rr < 8; rr++) {
    int ra = (rr + xcd) & 7;
    int idx = b * 4096 + ra * 512 + nl0;
    int j  = __builtin_amdgcn_readfirstlane(g_off8[idx]);
    int j1 = __builtin_amdgcn_readfirstlane(g_off8[idx + 16]);
    for (; j + 4 <= j1; j += 4) {
      uint v0 = (uint)__builtin_amdgcn_readfirstlane((int)g_csr[j + 0]);
      uint v1 = (uint)__builtin_amdgcn_readfirstlane((int)g_csr[j + 1]);
      uint v2 = (uint)__builtin_amdgcn_readfirstlane((int)g_csr[j + 2]);
      uint v3 = (uint)__builtin_amdgcn_readfirstlane((int)g_csr[j + 3]);
      int s0 = (int)(v0 & 0x1FFFFu), s1 = (int)(v1 & 0x1FFFFu);
      int s2 = (int)(v2 & 0x1FFFFu), s3 = (int)(v3 & 0x1FFFFu);
      float t0 = g_ssrc[s0 * NH + h];
      float t1 = g_ssrc[s1 * NH + h];
      float t2 = g_ssrc[s2 * NH + h];
      float t3 = g_ssrc[s3 * NH + h];
      uint f0 = h1u[s0 * HC1 + lane];
      uint f1 = h1u[s1 * HC1 + lane];
      uint f2 = h1u[s2 * HC1 + lane];
      uint f3 = h1u[s3 * HC1 + lane];
      float d0 = lsd[w][(int)(v0 >> 17) - nl0][h];
      float d1 = lsd[w][(int)(v1 >> 17) - nl0][h];
      float d2 = lsd[w][(int)(v2 >> 17) - nl0][h];
      float d3 = lsd[w][(int)(v3 >> 17) - nl0][h];
      float e0 = __expf(lrelu(t0 + d0));
      float e1 = __expf(lrelu(t1 + d1));
      float e2 = __expf(lrelu(t2 + d2));
      float e3 = __expf(lrelu(t3 + d3));
      EDGE1(v0, e0, f0);
      EDGE1(v1, e1, f1);
      EDGE1(v2, e2, f2);
      EDGE1(v3, e3, f3);
    }
    for (; j < j1; j++) {
      uint v = (uint)__builtin_amdgcn_readfirstlane((int)g_csr[j]);
      int sx = (int)(v & 0x1FFFFu);
      float t = g_ssrc[sx * NH + h];
      uint f = h1u[sx * HC1 + lane];
      float d = lsd[w][(int)(v >> 17) - nl0][h];
      float e = __expf(lrelu(t + d));
      EDGE1(v, e, f);
    }
    __syncthreads();  // keep the block's 4 waves phase-aligned
  }
  if (cur >= 0) {
    lacc[w][cur - nl0][lane] += acc;
    if (!(lane & 7)) lw[w][cur - nl0][h] += aw;
  }
#undef EDGE1
#pragma unroll
  for (int s = 0; s < 16; s++) {
    int n = n0 + s;
    if (n >= NN) break;
    float sd = lsd[w][s][h];
    float es = __expf(lrelu(g_ssrc[n * NH + h] + sd));
    float a = fmaf(g_h1[n * HC1 + lane], es, lacc[w][s][lane]);  // self loop fp32
    float ws = lw[w][s][h] + es;
    float v = a * (1.f / ws) + b1[lane];
    g_hact[n * HC1 + lane] = v > 0.f ? v : __expf(v) - 1.f;  // ELU
  }
}

// ---------------- GEMM2: g_h2 = g_hact[NN,64] @ W2[64,80] ----------------
__global__ __launch_bounds__(256) void gemm2_kernel(const float* __restrict__ W) {
  __shared__ float sW[64 * HC2 + 64];
  int tid = threadIdx.x;
  for (int i = tid; i < 64 * HC2; i += 256) sW[i] = W[i];
  for (int i = 64 * HC2 + tid; i < 64 * HC2 + 64; i += 256) sW[i] = 0.f;
  __syncthreads();
  int lane = tid & 63;
  int w0 = (blockIdx.x * 256 + tid) >> 6;
  for (int r = w0; r < NN; r += 8192) {
    float v = g_hact[r * HC1 + lane];
    float acc0 = 0.f, acc1 = 0.f;
#pragma unroll
    for (int k = 0; k < 64; k++) {
      float xk = __shfl(v, k);
      acc0 = fmaf(xk, sW[k * HC2 + lane], acc0);
      acc1 = fmaf(xk, sW[k * HC2 + 64 + lane], acc1);
    }
    g_h2[r * HC2 + lane] = acc0;
    if (lane < 16) g_h2[r * HC2 + 64 + lane] = acc1;
  }
}

// ---- layer-2 aggregation: 16 nodes/wave runs + bias + log_softmax ----------
__global__ __launch_bounds__(256) void agg2_kernel(float* __restrict__ out,
                                                   const float* __restrict__ b2) {
  __shared__ float lacc[4][16][80];  // node x 80 output channels
  __shared__ float lw[4][16][8];
  __shared__ float lsd[4][16][8];
  int tid = threadIdx.x;
  int w = tid >> 6, lane = tid & 63;
  int p = lane < 40 ? lane : 39;
  int h = p / 5;
  bool p5 = (lane < 40) && (lane % 5 == 0);  // one lane per head
  int wv = blockIdx.x * 4 + w;
  int n0 = wv * 16;
  int b = n0 >> 9, nl0 = n0 & 511;
#pragma unroll
  for (int s = 0; s < 16; s++) {
    if (lane < 40) {
      lacc[w][s][2 * lane] = 0.f;
      lacc[w][s][2 * lane + 1] = 0.f;
    }
  }
  for (int k = lane; k < 128; k += 64) {
    int s = k >> 3, hh = k & 7;
    int n = n0 + s; if (n >= NN) n = NN - 1;
    lsd[w][s][hh] = g_sdst[n * NH + hh];
    lw[w][s][hh] = 0.f;
  }
  int xcd = blockIdx.x & 7;
  int cur = -1;
  float a0 = 0.f, a1 = 0.f, aw = 0.f;
#define EDGE2(vv, ee, ff)                          \
  {                                                \
    int nl_ = (int)((vv) >> 17);                   \
    if (nl_ != cur) {                              \
      if (cur >= 0) {                              \
        int ss_ = cur - nl0;                       \
        if (lane < 40) {                           \
          lacc[w][ss_][2 * p] += a0;               \
          lacc[w][ss_][2 * p + 1] += a1;           \
        }                                          \
        if (p5) lw[w][ss_][h] += aw;               \
      }                                            \
      cur = nl_; a0 = 0.f; a1 = 0.f; aw = 0.f;     \
    }                                              \
    a0 = fmaf(blo(ff), (ee), a0);                  \
    a1 = fmaf(bhi(ff), (ee), a1);                  \
    aw += (ee);                                    \
  }
  for (int rr = 0; rr < 8; rr++) {
    int ra = (rr + xcd) & 7;
    int idx = b * 4096 + ra * 512 + nl0;
    int j  = __builtin_amdgcn_readfirstlane(g_off8[idx]);
    int j1 = __builtin_amdgcn_readfirstlane(g_off8[idx + 16]);
    for (; j + 4 <= j1; j += 4) {
      uint v0 = (uint)__builtin_amdgcn_readfirstlane((int)g_csr[j + 0]);
      uint v1 = (uint)__builtin_amdgcn_readfirstlane((int)g_csr[j + 1]);
      uint v2 = (uint)__builtin_amdgcn_readfirstlane((int)g_csr[j + 2]);
      uint v3 = (uint)__builtin_amdgcn_readfirstlane((int)g_csr[j + 3]);
      int s0 = (int)(v0 & 0x1FFFFu), s1 = (int)(v1 & 0x1FFFFu);
      int s2 = (int)(v2 & 0x1FFFFu), s3 = (int)(v3 & 0x1FFFFu);
      float t0 = g_ssrc[s0 * NH + h];
      float t1 = g_ssrc[s1 * NH + h];
      float t2 = g_ssrc[s2 * NH + h];
      float t3 = g_ssrc[s3 * NH + h];
      uint f0 = g_h2b[s0 * 40 + p];
      uint f1 = g_h2b[s1 * 40 + p];
      uint f2 = g_h2b[s2 * 40 + p];
      uint f3 = g_h2b[s3 * 40 + p];
      float d0 = lsd[w][(int)(v0 >> 17) - nl0][h];
      float d1 = lsd[w][(int)(v1 >> 17) - nl0][h];
      float d2 = lsd[w][(int)(v2 >> 17) - nl0][h];
      float d3 = lsd[w][(int)(v3 >> 17) - nl0][h];
      float e0 = __expf(lrelu(t0 + d0));
      float e1 = __expf(lrelu(t1 + d1));
      float e2 = __expf(lrelu(t2 + d2));
      float e3 = __expf(lrelu(t3 + d3));
      EDGE2(v0, e0, f0);
      EDGE2(v1, e1, f1);
      EDGE2(v2, e2, f2);
      EDGE2(v3, e3, f3);
    }
    for (; j < j1; j++) {
      uint v = (uint)__builtin_amdgcn_readfirstlane((int)g_csr[j]);
      int sx = (int)(v & 0x1FFFFu);
      float t = g_ssrc[sx * NH + h];
      uint f = g_h2b[sx * 40 + p];
      float d = lsd[w][(int)(v >> 17) - nl0][h];
      float e = __expf(lrelu(t + d));
      EDGE2(v, e, f);
    }
    __syncthreads();  // keep the block's 4 waves phase-aligned
  }
  if (cur >= 0) {
    int ss_ = cur - nl0;
    if (lane < 40) {
      lacc[w][ss_][2 * p] += a0;
      lacc[w][ss_][2 * p + 1] += a1;
    }
    if (p5) lw[w][ss_][h] += aw;
  }
#undef EDGE2
#pragma unroll
  for (int s = 0; s < 16; s++) {
    int n = n0 + s;
    if (n >= NN) break;
    float sd = lsd[w][s][h];
    float es = __expf(lrelu(g_ssrc[n * NH + h] + sd));
    float x0 = fmaf(g_h2[n * HC2 + 2 * p], es, lacc[w][s][2 * p]);
    float x1 = fmaf(g_h2[n * HC2 + 2 * p + 1], es, lacc[w][s][2 * p + 1]);
    float ws = lw[w][s][h] + es;
    float inv = 1.f / ws;
    float v0 = x0 * inv + b2[2 * p];
    float v1 = x1 * inv + b2[2 * p + 1];
    float mx = fmaxf(v0, v1);
    for (int o = 32; o; o >>= 1) mx = fmaxf(mx, __shfl_xor(mx, o));
    float spart = (lane < 40) ? __expf(v0 - mx) + __expf(v1 - mx) : 0.f;
    for (int o = 32; o; o >>= 1) spart += __shfl_xor(spart, o);
    float lse = mx + __logf(spart);
    if (lane < 40) *(float2*)&out[n * HC2 + 2 * p] = make_float2(v0 - lse, v1 - lse);
  }
}

// ---------------- launch ----------------
extern "C" void kernel_launch(void* const* d_in, const int* in_sizes, int n_in,
                              void* d_out, int out_size, void* d_ws, size_t ws_size,
                              hipStream_t stream) {
  (void)in_sizes; (void)n_in; (void)out_size; (void)d_ws; (void)ws_size;
  const float* x   = (const float*)d_in[0];
  const int*   ei  = (const int*)d_in[1];
  const float* W1  = (const float*)d_in[2];
  const float* as1 = (const float*)d_in[3];
  const float* ad1 = (const float*)d_in[4];
  const float* b1  = (const float*)d_in[5];
  const float* W2  = (const float*)d_in[6];
  const float* as2 = (const float*)d_in[7];
  const float* ad2 = (const float*)d_in[8];
  const float* b2  = (const float*)d_in[9];
  float* out = (float*)d_out;

  // CSR build (radix partition + (range,node) ordering; shared by both layers)
  p1count_kernel<<<NBLK, 256, 0, stream>>>(ei);
  scn_block_kernel<<<SCNB, 1024, 0, stream>>>();
  scn_tops_kernel<<<1, 256, 0, stream>>>();
  scn_add_kernel<<<SCNB, 1024, 0, stream>>>();
  p1scatter_kernel<<<NBLK, 256, 0, stream>>>(ei);
  p2build_kernel<<<NBUK, 1024, 0, stream>>>();

  // layer 1
  w1cast_kernel<<<64, 256, 0, stream>>>(W1);
  gemm1_kernel<<<1563, 256, 0, stream>>>(x);
  s_kernel<1><<<3125, 256, 0, stream>>>(as1, ad1);
  agg1_kernel<<<AGGB, 256, 0, stream>>>(b1);

  // layer 2
  gemm2_kernel<<<2048, 256, 0, stream>>>(W2);
  s_kernel<2><<<3125, 256, 0, stream>>>(as2, ad2);
  agg2_kernel<<<AGGB, 256, 0, stream>>>(out, b2);
}

// Round 5
// 785.469 us; speedup vs baseline: 1.1768x; 1.1768x over previous
//
#include <hip/hip_runtime.h>
#include <math.h>

#define NN 100000
#define NE 3200000
#define FIN 512
#define NH 8
#define C1 8
#define HC1 64
#define C2 10
#define HC2 80

// radix CSR build
#define EPB 4096
#define NBLK 782           // ceil(NE/EPB)
#define NBUK 196           // ceil(NN/512)
#define SCN (NBUK * NBLK)  // 153272
#define SCNB 150           // ceil(SCN/1024)

typedef unsigned int uint;
typedef unsigned short ushort;
using bf16x8 = __attribute__((ext_vector_type(8))) short;
using f32x4  = __attribute__((ext_vector_type(4))) float;

#define RFL(x) __builtin_amdgcn_readfirstlane((int)(x))

// ---------------- static scratch ----------------
__device__ float g_h1[NN * HC1];        // x @ W1 (fp32, MFMA out)
__device__ float g_hact[NN * HC1];      // elu(agg1 + b1)
__device__ float g_h2[NN * HC2];        // hact @ W2 (fp32)
__device__ uint  g_h1b[NN * 32];        // h1 as bf16 pairs (uint k: chs 2k,2k+1)
__device__ uint  g_h2b[NN * 40];        // h2 bf16, permuted split layout (see s_kernel<2>)
__device__ uint  g_w1bt[64 * 256];      // W1 transposed bf16 pairs: [n][kp]
__device__ float g_ssrc[NN * NH];
__device__ float g_sdst[NN * NH];
__device__ int   g_off[NN + 1];
__device__ uint  g_pscan[SCN];          // per-(bucket,block) counts -> scanned
__device__ uint  g_bsum2[256];
__device__ uint  g_ebuf[NE];            // packed (dlow<<17)|src, bucket-partitioned
__device__ int   g_csr[NE];

__device__ __forceinline__ float lrelu(float x) { return fmaxf(x, 0.2f * x); }

__device__ __forceinline__ uint bf16_rne(float x) {
  uint u = __float_as_uint(x);
  u += 0x7fffu + ((u >> 16) & 1u);
  return u >> 16;
}
__device__ __forceinline__ uint packbf2(float lo, float hi) {
  return bf16_rne(lo) | (bf16_rne(hi) << 16);
}
__device__ __forceinline__ float blo(uint v) { return __uint_as_float(v << 16); }
__device__ __forceinline__ float bhi(uint v) { return __uint_as_float(v & 0xffff0000u); }

// ---------------- CSR build: radix partition by dst, no global atomics ----------
__global__ __launch_bounds__(256) void p1count_kernel(const int* __restrict__ ei) {
  __shared__ uint cnt[NBUK];
  int tid = threadIdx.x;
  for (int i = tid; i < NBUK; i += 256) cnt[i] = 0;
  __syncthreads();
  const int* dstp = ei + NE;
  int base = blockIdx.x * EPB;
#pragma unroll 4
  for (int k = 0; k < 16; k++) {
    int e = base + k * 256 + tid;
    if (e < NE) atomicAdd(&cnt[dstp[e] >> 9], 1u);
  }
  __syncthreads();
  for (int i = tid; i < NBUK; i += 256) g_pscan[i * NBLK + blockIdx.x] = cnt[i];
}

__global__ __launch_bounds__(1024) void scn_block_kernel() {
  __shared__ uint sd[1024];
  int tid = threadIdx.x;
  int i = blockIdx.x * 1024 + tid;
  uint v = (i < SCN) ? g_pscan[i] : 0;
  sd[tid] = v;
  __syncthreads();
  for (int off = 1; off < 1024; off <<= 1) {
    uint x = (tid >= off) ? sd[tid - off] : 0;
    __syncthreads();
    sd[tid] += x;
    __syncthreads();
  }
  if (i < SCN) g_pscan[i] = sd[tid] - v;  // exclusive within block
  if (tid == 1023) g_bsum2[blockIdx.x] = sd[1023];
}

__global__ void scn_tops_kernel() {  // 1 block, 256 threads
  __shared__ uint sd[256];
  int tid = threadIdx.x;
  uint v = (tid < SCNB) ? g_bsum2[tid] : 0;
  sd[tid] = v;
  __syncthreads();
  for (int off = 1; off < 256; off <<= 1) {
    uint x = (tid >= off) ? sd[tid - off] : 0;
    __syncthreads();
    sd[tid] += x;
    __syncthreads();
  }
  g_bsum2[tid] = sd[tid] - v;  // exclusive scan of block sums
}

__global__ __launch_bounds__(1024) void scn_add_kernel() {
  int i = blockIdx.x * 1024 + threadIdx.x;
  if (i < SCN) g_pscan[i] += g_bsum2[i >> 10];
}

__global__ __launch_bounds__(256) void p1scatter_kernel(const int* __restrict__ ei) {
  __shared__ uint cur[NBUK];
  int tid = threadIdx.x;
  for (int i = tid; i < NBUK; i += 256) cur[i] = g_pscan[i * NBLK + blockIdx.x];
  __syncthreads();
  const int* srcp = ei;
  const int* dstp = ei + NE;
  int base = blockIdx.x * EPB;
#pragma unroll 4
  for (int k = 0; k < 16; k++) {
    int e = base + k * 256 + tid;
    if (e < NE) {
      int d = dstp[e], s = srcp[e];
      uint pos = atomicAdd(&cur[d >> 9], 1u);  // LDS atomic
      g_ebuf[pos] = ((uint)(d & 511) << 17) | (uint)s;
    }
  }
}

// Pass 2: per-bucket 4096-bin (dlow x src-range) histogram/scan/scatter.
// Within-node edge lists come out ordered by src>>14 (8 ranges of 16K nodes)
// -> agg kernels sweep src ranges in order => XCD-L2 locality for the gathers.
__global__ __launch_bounds__(1024) void p2build_kernel() {
  __shared__ uint hist[4096];   // reused as cursors in pass 2
  __shared__ uint excl[4096];
  __shared__ uint tsum[1024];
  int tid = threadIdx.x;
  int b = blockIdx.x;
  uint bstart = g_pscan[b * NBLK];
  uint bend = (b < NBUK - 1) ? g_pscan[(b + 1) * NBLK] : NE;
  for (int i = tid; i < 4096; i += 1024) hist[i] = 0;
  __syncthreads();
  for (uint j = bstart + tid; j < bend; j += 1024) {
    uint v = g_ebuf[j];
    uint bin = ((v >> 17) << 3) | ((v & 0x1FFFFu) >> 14);
    atomicAdd(&hist[bin], 1u);
  }
  __syncthreads();
  uint h0 = hist[tid * 4 + 0], h1 = hist[tid * 4 + 1];
  uint h2 = hist[tid * 4 + 2], h3 = hist[tid * 4 + 3];
  uint s1 = h0 + h1, s2 = s1 + h2, s3 = s2 + h3;
  tsum[tid] = s3;
  __syncthreads();
  for (int off = 1; off < 1024; off <<= 1) {
    uint x = (tid >= off) ? tsum[tid - off] : 0;
    __syncthreads();
    tsum[tid] += x;
    __syncthreads();
  }
  uint te = tsum[tid] - s3;  // exclusive over threads
  excl[tid * 4 + 0] = te;
  excl[tid * 4 + 1] = te + h0;
  excl[tid * 4 + 2] = te + s1;
  excl[tid * 4 + 3] = te + s2;
  __syncthreads();
  if (tid < 512) {
    int dst = b * 512 + tid;
    if (dst < NN) g_off[dst] = (int)(bstart + excl[tid * 8]);
  }
  if (b == NBUK - 1 && tid == 0) g_off[NN] = NE;
  for (int i = tid; i < 4096; i += 1024) hist[i] = excl[i];  // cursors
  __syncthreads();
  for (uint j = bstart + tid; j < bend; j += 1024) {
    uint v = g_ebuf[j];
    uint bin = ((v >> 17) << 3) | ((v & 0x1FFFFu) >> 14);
    uint pos = bstart + atomicAdd(&hist[bin], 1u);  // LDS atomic
    g_csr[pos] = (int)(v & 0x1FFFFu);
  }
}

// ---------------- W1 -> bf16 transposed pairs ----------------
__global__ __launch_bounds__(256) void w1cast_kernel(const float* __restrict__ W) {
  int idx = blockIdx.x * 256 + threadIdx.x;  // 0..16383
  int n = idx & 63, kp = idx >> 6;           // kp 0..255
  float lo = W[(2 * kp) * HC1 + n];
  float hi = W[(2 * kp + 1) * HC1 + n];
  g_w1bt[n * 256 + kp] = packbf2(lo, hi);
}

// ---------------- GEMM1: g_h1 = X[NN,512] @ W1[512,64] via bf16 MFMA ------------
__device__ __forceinline__ int sw_idx(int row, int g) {
  return row * 32 + ((g ^ (row & 7)) << 2);
}

__global__ __launch_bounds__(256) void gemm1_kernel(const float* __restrict__ X) {
  __shared__ uint sA[64 * 32];
  __shared__ uint sB[64 * 32];
  int t = threadIdx.x;
  int w = t >> 6, l = t & 63;
  int q = l >> 4, c = l & 15;
  int r0 = blockIdx.x * 64;
  int sr = t >> 2;             // 0..63 (row / n)
  int sc = t & 3;              // quarter
  int xrow = r0 + sr; if (xrow >= NN) xrow = NN - 1;
  const float* xbase = &X[(long)xrow * FIN + sc * 16];
  const uint* wbase = &g_w1bt[sr * 256 + sc * 8];
  f32x4 acc[4] = {{0.f,0.f,0.f,0.f},{0.f,0.f,0.f,0.f},{0.f,0.f,0.f,0.f},{0.f,0.f,0.f,0.f}};
  for (int k0 = 0; k0 < FIN; k0 += 64) {
    __syncthreads();
    float4 f0 = *(const float4*)&xbase[k0 + 0];
    float4 f1 = *(const float4*)&xbase[k0 + 4];
    float4 f2 = *(const float4*)&xbase[k0 + 8];
    float4 f3 = *(const float4*)&xbase[k0 + 12];
    uint4 a0 = make_uint4(packbf2(f0.x, f0.y), packbf2(f0.z, f0.w),
                          packbf2(f1.x, f1.y), packbf2(f1.z, f1.w));
    uint4 a1 = make_uint4(packbf2(f2.x, f2.y), packbf2(f2.z, f2.w),
                          packbf2(f3.x, f3.y), packbf2(f3.z, f3.w));
    *(uint4*)&sA[sw_idx(sr, sc * 2 + 0)] = a0;
    *(uint4*)&sA[sw_idx(sr, sc * 2 + 1)] = a1;
    uint4 b0 = *(const uint4*)&wbase[(k0 >> 1) + 0];
    uint4 b1 = *(const uint4*)&wbase[(k0 >> 1) + 4];
    *(uint4*)&sB[sw_idx(sr, sc * 2 + 0)] = b0;
    *(uint4*)&sB[sw_idx(sr, sc * 2 + 1)] = b1;
    __syncthreads();
#pragma unroll
    for (int ks = 0; ks < 2; ks++) {
      int g = ks * 4 + q;
      bf16x8 a = *(const bf16x8*)&sA[sw_idx(w * 16 + c, g)];
#pragma unroll
      for (int nt = 0; nt < 4; nt++) {
        bf16x8 b = *(const bf16x8*)&sB[sw_idx(nt * 16 + c, g)];
        acc[nt] = __builtin_amdgcn_mfma_f32_16x16x32_bf16(a, b, acc[nt], 0, 0, 0);
      }
    }
  }
  int orow0 = r0 + w * 16 + q * 4;
#pragma unroll
  for (int nt = 0; nt < 4; nt++) {
#pragma unroll
    for (int r = 0; r < 4; r++) {
      int row = orow0 + r;
      if (row < NN) g_h1[row * HC1 + nt * 16 + c] = acc[nt][r];
    }
  }
}

// ---------------- attention scores + bf16 packing ----------------
// Layer 1: g_h1b uint k (0..31) = chs 2k,2k+1   (lane il reads uint2 -> chs 4il..4il+3)
// Layer 2: permuted split layout for the 4-slot agg2:
//   A (uints 0..31):  uints 2*il, 2*il+1 = chs 10*(il>>1) + 5*(il&1) + {0,1,2,3}
//   B (bytes 128..159 as 16 ushorts): ushort il = ch 10*(il>>1) + 5*(il&1) + 4
template <int LAYER>
__global__ __launch_bounds__(256) void s_kernel(const float* __restrict__ a_src,
                                                const float* __restrict__ a_dst) {
  constexpr int C = (LAYER == 1) ? C1 : C2;
  const float* Hm = (LAYER == 1) ? g_h1 : g_h2;
  int t = blockIdx.x * 256 + threadIdx.x;
  if (t >= NN * NH) return;
  int h = t & 7;
  const float* row = &Hm[t * C];
  float ss = 0.f, sdd = 0.f;
  float vals[C];
#pragma unroll
  for (int c = 0; c < C; c++) {
    float v = row[c];
    vals[c] = v;
    ss = fmaf(v, a_src[h * C + c], ss);
    sdd = fmaf(v, a_dst[h * C + c], sdd);
  }
  g_ssrc[t] = ss;
  g_sdst[t] = sdd;
  if constexpr (LAYER == 1) {
#pragma unroll
    for (int j = 0; j < 4; j++)
      g_h1b[t * 4 + j] = packbf2(vals[2 * j], vals[2 * j + 1]);
  } else {
    int n = t >> 3;
#pragma unroll
    for (int b = 0; b < 2; b++) {
      int il = 2 * h + b;
      g_h2b[n * 40 + 2 * il + 0] = packbf2(vals[5 * b + 0], vals[5 * b + 1]);
      g_h2b[n * 40 + 2 * il + 1] = packbf2(vals[5 * b + 2], vals[5 * b + 3]);
      ((ushort*)&g_h2b[n * 40 + 32])[il] = (ushort)bf16_rne(vals[5 * b + 4]);
    }
  }
}

// ---- layer-1 aggregation: wave/node, 4 edge-slots x 16 lanes x 4 channels ----
// Per 4 edges: 1 exp, 1 score chain, 4 fma (all 64 lanes useful). Slot partials
// merged by shfl_xor(16/32) butterfly. Two register chains (A/B) for MLP.
__global__ __launch_bounds__(256) void agg1_kernel(const float* __restrict__ b1) {
  int gw = RFL((blockIdx.x * 256 + threadIdx.x) >> 6);
  if (gw >= NN) return;
  int lane = threadIdx.x & 63;
  int sl = lane >> 4, il = lane & 15;
  int hh = il >> 1;
  bool sl1 = (sl & 1) != 0, sl2 = (sl & 2) != 0;
  float sdl = g_sdst[gw * NH + hh];
  float4 bb = *(const float4*)&b1[4 * il];
  int j = g_off[gw];
  int jend = g_off[gw + 1];
  if (jend < j) jend = j;  // defensive clamp
  float a0A=0.f,a1A=0.f,a2A=0.f,a3A=0.f,wA=0.f;
  float a0B=0.f,a1B=0.f,a2B=0.f,a3B=0.f,wB=0.f;
#define G1(A0,A1,A2,A3,WW,J) {                                       \
    int s0 = RFL(g_csr[(J)+0]), s1 = RFL(g_csr[(J)+1]);              \
    int s2 = RFL(g_csr[(J)+2]), s3 = RFL(g_csr[(J)+3]);              \
    int ssx = sl2 ? (sl1 ? s3 : s2) : (sl1 ? s1 : s0);               \
    float tt = g_ssrc[ssx * NH + hh];                                \
    uint2 va = *(const uint2*)&g_h1b[ssx * 32 + 2 * il];             \
    float e = __expf(lrelu(tt + sdl));                               \
    A0 = fmaf(blo(va.x), e, A0); A1 = fmaf(bhi(va.x), e, A1);        \
    A2 = fmaf(blo(va.y), e, A2); A3 = fmaf(bhi(va.y), e, A3);        \
    WW += e; }
  for (; j + 8 <= jend; j += 8) {
    G1(a0A,a1A,a2A,a3A,wA,j)
    G1(a0B,a1B,a2B,a3B,wB,j+4)
  }
  if (j + 4 <= jend) { G1(a0A,a1A,a2A,a3A,wA,j); j += 4; }
#undef G1
  // robust per-edge tail (<=3 iters): slot 0 accumulates, others add 0
  for (; j < jend; j++) {
    int s0 = RFL(g_csr[j]);
    float tt = g_ssrc[s0 * NH + hh];
    uint2 va = *(const uint2*)&g_h1b[s0 * 32 + 2 * il];
    float e = (sl == 0) ? __expf(lrelu(tt + sdl)) : 0.f;
    a0B = fmaf(blo(va.x), e, a0B); a1B = fmaf(bhi(va.x), e, a1B);
    a2B = fmaf(blo(va.y), e, a2B); a3B = fmaf(bhi(va.y), e, a3B);
    wB += e;
  }
  float a0 = a0A + a0B, a1 = a1A + a1B, a2 = a2A + a2B, a3 = a3A + a3B;
  float w = wA + wB;
  a0 += __shfl_xor(a0, 16); a0 += __shfl_xor(a0, 32);
  a1 += __shfl_xor(a1, 16); a1 += __shfl_xor(a1, 32);
  a2 += __shfl_xor(a2, 16); a2 += __shfl_xor(a2, 32);
  a3 += __shfl_xor(a3, 16); a3 += __shfl_xor(a3, 32);
  w  += __shfl_xor(w, 16);  w  += __shfl_xor(w, 32);
  float es = __expf(lrelu(g_ssrc[gw * NH + hh] + sdl));
  float4 hv = *(const float4*)&g_h1[gw * HC1 + 4 * il];  // self loop fp32
  a0 = fmaf(hv.x, es, a0); a1 = fmaf(hv.y, es, a1);
  a2 = fmaf(hv.z, es, a2); a3 = fmaf(hv.w, es, a3);
  w += es;
  float inv = 1.f / w;
  float v0 = a0 * inv + bb.x, v1 = a1 * inv + bb.y;
  float v2 = a2 * inv + bb.z, v3 = a3 * inv + bb.w;
  v0 = v0 > 0.f ? v0 : __expf(v0) - 1.f;
  v1 = v1 > 0.f ? v1 : __expf(v1) - 1.f;
  v2 = v2 > 0.f ? v2 : __expf(v2) - 1.f;
  v3 = v3 > 0.f ? v3 : __expf(v3) - 1.f;
  if (sl == 0) *(float4*)&g_hact[gw * HC1 + 4 * il] = make_float4(v0, v1, v2, v3);
}

// ---------------- GEMM2: g_h2 = g_hact[NN,64] @ W2[64,80] ----------------
__global__ __launch_bounds__(256) void gemm2_kernel(const float* __restrict__ W) {
  __shared__ float sW[64 * HC2 + 64];
  int tid = threadIdx.x;
  for (int i = tid; i < 64 * HC2; i += 256) sW[i] = W[i];
  for (int i = 64 * HC2 + tid; i < 64 * HC2 + 64; i += 256) sW[i] = 0.f;
  __syncthreads();
  int lane = tid & 63;
  int w0 = (blockIdx.x * 256 + tid) >> 6;
  for (int r = w0; r < NN; r += 8192) {
    float v = g_hact[r * HC1 + lane];
    float acc0 = 0.f, acc1 = 0.f;
#pragma unroll
    for (int k = 0; k < 64; k++) {
      float xk = __shfl(v, k);
      acc0 = fmaf(xk, sW[k * HC2 + lane], acc0);
      acc1 = fmaf(xk, sW[k * HC2 + 64 + lane], acc1);
    }
    g_h2[r * HC2 + lane] = acc0;
    if (lane < 16) g_h2[r * HC2 + 64 + lane] = acc1;
  }
}

// ---- layer-2 aggregation: 4 edge-slots x 16 lanes x 5 channels + log_softmax --
__global__ __launch_bounds__(256) void agg2_kernel(float* __restrict__ out,
                                                   const float* __restrict__ b2) {
  int gw = RFL((blockIdx.x * 256 + threadIdx.x) >> 6);
  if (gw >= NN) return;
  int lane = threadIdx.x & 63;
  int sl = lane >> 4, il = lane & 15;
  int hh = il >> 1, bq = il & 1;
  int c0 = 10 * hh + 5 * bq;  // first true channel of this lane
  bool sl1 = (sl & 1) != 0, sl2 = (sl & 2) != 0;
  float sdl = g_sdst[gw * NH + hh];
  float bb0 = b2[c0 + 0], bb1 = b2[c0 + 1], bb2 = b2[c0 + 2];
  float bb3 = b2[c0 + 3], bb4 = b2[c0 + 4];
  int j = g_off[gw];
  int jend = g_off[gw + 1];
  if (jend < j) jend = j;  // defensive clamp
  float a0A=0.f,a1A=0.f,a2A=0.f,a3A=0.f,a4A=0.f,wA=0.f;
  float a0B=0.f,a1B=0.f,a2B=0.f,a3B=0.f,a4B=0.f,wB=0.f;
#define G2(A0,A1,A2,A3,A4,WW,J) {                                    \
    int s0 = RFL(g_csr[(J)+0]), s1 = RFL(g_csr[(J)+1]);              \
    int s2 = RFL(g_csr[(J)+2]), s3 = RFL(g_csr[(J)+3]);              \
    int ssx = sl2 ? (sl1 ? s3 : s2) : (sl1 ? s1 : s0);               \
    float tt = g_ssrc[ssx * NH + hh];                                \
    uint2 va = *(const uint2*)&g_h2b[ssx * 40 + 2 * il];             \
    uint vb = ((const ushort*)&g_h2b[ssx * 40 + 32])[il];            \
    float e = __expf(lrelu(tt + sdl));                               \
    A0 = fmaf(blo(va.x), e, A0); A1 = fmaf(bhi(va.x), e, A1);        \
    A2 = fmaf(blo(va.y), e, A2); A3 = fmaf(bhi(va.y), e, A3);        \
    A4 = fmaf(__uint_as_float(vb << 16), e, A4);                     \
    WW += e; }
  for (; j + 8 <= jend; j += 8) {
    G2(a0A,a1A,a2A,a3A,a4A,wA,j)
    G2(a0B,a1B,a2B,a3B,a4B,wB,j+4)
  }
  if (j + 4 <= jend) { G2(a0A,a1A,a2A,a3A,a4A,wA,j); j += 4; }
#undef G2
  // robust per-edge tail (<=3 iters): slot 0 accumulates, others add 0
  for (; j < jend; j++) {
    int s0 = RFL(g_csr[j]);
    float tt = g_ssrc[s0 * NH + hh];
    uint2 va = *(const uint2*)&g_h2b[s0 * 40 + 2 * il];
    uint vb = ((const ushort*)&g_h2b[s0 * 40 + 32])[il];
    float e = (sl == 0) ? __expf(lrelu(tt + sdl)) : 0.f;
    a0B = fmaf(blo(va.x), e, a0B); a1B = fmaf(bhi(va.x), e, a1B);
    a2B = fmaf(blo(va.y), e, a2B); a3B = fmaf(bhi(va.y), e, a3B);
    a4B = fmaf(__uint_as_float(vb << 16), e, a4B);
    wB += e;
  }
  float a0 = a0A + a0B, a1 = a1A + a1B, a2 = a2A + a2B;
  float a3 = a3A + a3B, a4 = a4A + a4B, w = wA + wB;
  a0 += __shfl_xor(a0, 16); a0 += __shfl_xor(a0, 32);
  a1 += __shfl_xor(a1, 16); a1 += __shfl_xor(a1, 32);
  a2 += __shfl_xor(a2, 16); a2 += __shfl_xor(a2, 32);
  a3 += __shfl_xor(a3, 16); a3 += __shfl_xor(a3, 32);
  a4 += __shfl_xor(a4, 16); a4 += __shfl_xor(a4, 32);
  w  += __shfl_xor(w, 16);  w  += __shfl_xor(w, 32);
  float es = __expf(lrelu(g_ssrc[gw * NH + hh] + sdl));
  const float* h2row = &g_h2[gw * HC2 + c0];  // self loop fp32
  a0 = fmaf(h2row[0], es, a0); a1 = fmaf(h2row[1], es, a1);
  a2 = fmaf(h2row[2], es, a2); a3 = fmaf(h2row[3], es, a3);
  a4 = fmaf(h2row[4], es, a4);
  w += es;
  float inv = 1.f / w;
  float v0 = a0 * inv + bb0, v1 = a1 * inv + bb1, v2 = a2 * inv + bb2;
  float v3 = a3 * inv + bb3, v4 = a4 * inv + bb4;
  // log_softmax over the 80 chs spread across the 16-lane group
  float mx = fmaxf(fmaxf(fmaxf(v0, v1), fmaxf(v2, v3)), v4);
  for (int o = 1; o < 16; o <<= 1) mx = fmaxf(mx, __shfl_xor(mx, o));
  float sp = __expf(v0 - mx) + __expf(v1 - mx) + __expf(v2 - mx) +
             __expf(v3 - mx) + __expf(v4 - mx);
  for (int o = 1; o < 16; o <<= 1) sp += __shfl_xor(sp, o);
  float lse = mx + __logf(sp);
  if (sl == 0) {
    float* op = &out[gw * HC2 + c0];
    op[0] = v0 - lse; op[1] = v1 - lse; op[2] = v2 - lse;
    op[3] = v3 - lse; op[4] = v4 - lse;
  }
}

// ---------------- launch ----------------
extern "C" void kernel_launch(void* const* d_in, const int* in_sizes, int n_in,
                              void* d_out, int out_size, void* d_ws, size_t ws_size,
                              hipStream_t stream) {
  (void)in_sizes; (void)n_in; (void)out_size; (void)d_ws; (void)ws_size;
  const float* x   = (const float*)d_in[0];
  const int*   ei  = (const int*)d_in[1];
  const float* W1  = (const float*)d_in[2];
  const float* as1 = (const float*)d_in[3];
  const float* ad1 = (const float*)d_in[4];
  const float* b1  = (const float*)d_in[5];
  const float* W2  = (const float*)d_in[6];
  const float* as2 = (const float*)d_in[7];
  const float* ad2 = (const float*)d_in[8];
  const float* b2  = (const float*)d_in[9];
  float* out = (float*)d_out;

  // CSR build (radix partition + src-range ordering; shared by both layers)
  p1count_kernel<<<NBLK, 256, 0, stream>>>(ei);
  scn_block_kernel<<<SCNB, 1024, 0, stream>>>();
  scn_tops_kernel<<<1, 256, 0, stream>>>();
  scn_add_kernel<<<SCNB, 1024, 0, stream>>>();
  p1scatter_kernel<<<NBLK, 256, 0, stream>>>(ei);
  p2build_kernel<<<NBUK, 1024, 0, stream>>>();

  // layer 1
  w1cast_kernel<<<64, 256, 0, stream>>>(W1);
  gemm1_kernel<<<1563, 256, 0, stream>>>(x);
  s_kernel<1><<<3125, 256, 0, stream>>>(as1, ad1);
  agg1_kernel<<<25000, 256, 0, stream>>>(b1);

  // layer 2
  gemm2_kernel<<<2048, 256, 0, stream>>>(W2);
  s_kernel<2><<<3125, 256, 0, stream>>>(as2, ad2);
  agg2_kernel<<<25000, 256, 0, stream>>>(out, b2);
}